// Round 2
// baseline (454.388 us; speedup 1.0000x reference)
//
#include <hip/hip_runtime.h>
#include <math.h>

// ---------------------------------------------------------------------------
// Input_level_Adapeter pipeline, round 12 (transcendental pass):
//  - conv_s2 / denoise_conv1 / attn / wb_finalize = round 11 verbatim.
//  - final_kernel v3:
//      * tanh via exp2f(x*2*log2e) — folds __expf's internal mul (1 mul saved)
//      * Montgomery batch-rcp over each MFMA quad d[0..3]: ONE v_rcp_f32 per
//        4 tanh instead of 4 (8 trans -> 5 trans per quad, +5 full-rate).
//        fminf(z,30) clamp guarantees finite products (f16 output unchanged).
//      * everything else (ROW=40 layout, wave-local waits, preconverted whf)
//        unchanged. Numerics delta ~1e-6 abs -> absmax should stay 0.00390625.
//  - wb_reduce: pow via exp2f(d*log2f(v)) instead of __expf(d*__logf(v))
//    (saves 2 muls/element, same trans count).
// d_out doubles as the I2 buffer.
// ---------------------------------------------------------------------------

#define BN_MUL 0.9999950000374997f   // 1/sqrt(1+1e-5)

static constexpr int BB   = 8;
static constexpr int HH   = 512;
static constexpr int WW   = 512;
static constexpr int HW   = HH * WW;
static constexpr int NTOK = 1024;    // (512/16)^2
static constexpr int DIMC = 64;
static constexpr int WBCH = 32;      // wb_reduce chunks per (b,c)

typedef _Float16 f16x8 __attribute__((ext_vector_type(8)));
typedef _Float16 f16x2 __attribute__((ext_vector_type(2)));
typedef float    f32x4 __attribute__((ext_vector_type(4)));

__device__ __forceinline__ float gelu_exact(float x) {
    return 0.5f * x * (1.0f + erff(x * 0.7071067811865476f));
}

// --- stride-2 3x3 conv + bias + BN (+ optional exact GELU), zero padding ---
// [round 6 verbatim] grid: (Hout*Wout/256, Cout/OCT, B).
template<int Cin, int Hin, int OCT, bool GELU>
__global__ __launch_bounds__(256) void conv_s2(const float* __restrict__ in,
                                               const float* __restrict__ wt,
                                               const float* __restrict__ bs,
                                               float* __restrict__ out)
{
    constexpr int Win  = Hin, Hout = Hin / 2, Wout = Hin / 2;
    constexpr int WSH  = (Wout == 256) ? 8 : (Wout == 128) ? 7 : (Wout == 64) ? 6 : 5;
    constexpr int PLANE = Hout * Wout;

    const int sp  = blockIdx.x * 256 + threadIdx.x;
    const int ow  = sp & (Wout - 1);
    const int oh  = sp >> WSH;
    const int oc0 = blockIdx.y * OCT;
    const int b   = blockIdx.z;
    const int Cout = (int)gridDim.y * OCT;

    float acc[OCT];
    #pragma unroll
    for (int o = 0; o < OCT; ++o) acc[o] = bs[oc0 + o];

    const int ih0 = oh * 2 - 1, iw0 = ow * 2 - 1;
    const float fh0 = (ih0 >= 0) ? 1.f : 0.f;
    const float fw0 = (iw0 >= 0) ? 1.f : 0.f;
    const int r0 = (ih0 >= 0) ? ih0 : 0;
    const int cc0 = (iw0 >= 0) ? iw0 : 0;

    const float* ip = in + (size_t)(b * Cin) * Hin * Win;
    #pragma unroll
    for (int ic = 0; ic < Cin; ++ic) {
        const float* pl = ip + ic * Hin * Win;
        const float* p0 = pl + r0 * Win;
        const float* p1 = pl + (ih0 + 1) * Win;
        const float* p2 = pl + (ih0 + 2) * Win;
        float  v00 = p0[cc0] * (fh0 * fw0);
        float2 va  = *(const float2*)(p0 + iw0 + 1);
        float  v01 = va.x * fh0, v02 = va.y * fh0;
        float  v10 = p1[cc0] * fw0;
        float2 vb  = *(const float2*)(p1 + iw0 + 1);
        float  v20 = p2[cc0] * fw0;
        float2 vc  = *(const float2*)(p2 + iw0 + 1);
        #pragma unroll
        for (int o = 0; o < OCT; ++o) {
            const float* wr = wt + ((oc0 + o) * Cin + ic) * 9;   // uniform -> s_load
            acc[o] += v00 * wr[0] + v01 * wr[1] + v02 * wr[2]
                    + v10 * wr[3] + vb.x * wr[4] + vb.y * wr[5]
                    + v20 * wr[6] + vc.x * wr[7] + vc.y * wr[8];
        }
    }
    #pragma unroll
    for (int o = 0; o < OCT; ++o) {
        float a = acc[o] * BN_MUL;
        if (GELU) a = gelu_exact(a);
        out[(size_t)(b * Cout + oc0 + o) * PLANE + sp] = a;
    }
}

// --- fused denoise + conv1_mp --- [round 6 verbatim]
__global__ __launch_bounds__(256) void denoise_conv1_kernel(
    const float* __restrict__ I1, const float* __restrict__ attno,
    const float* __restrict__ gain_base,
    const float* __restrict__ wt, const float* __restrict__ bs,
    float* __restrict__ I2, float* __restrict__ out)
{
    const int sp = blockIdx.x * 256 + threadIdx.x;
    const int ow = sp & 255;
    const int oh = sp >> 8;
    const int b  = blockIdx.z;

    const float o0 = attno[b * 4 + 0], o1 = attno[b * 4 + 1];
    const float o2 = attno[b * 4 + 2], o3 = attno[b * 4 + 3];
    const float r1 = 0.1f * o0 + 3.0f;
    const float r2 = 0.1f * o1 + 2.0f;
    const float g  = o2 + gain_base[0];
    const float sg = 1.0f / (1.0f + __expf(-o3));
    const float ex = __expf(-0.5f / (r1 * r1));
    const float nx = 1.0f / (2.0f * ex + 1.0f);
    const float ey = __expf(-0.5f / (r2 * r2));
    const float ny = 1.0f / (2.0f * ey + 1.0f);
    const float kx0 = ex * nx, kx1 = nx;
    const float ky0 = ey * ny, ky1 = ny;

    const int rbase = 2 * oh - 2, cbase = 2 * ow - 2;
    int ri[5], ci[5];
    #pragma unroll
    for (int i = 0; i < 5; ++i) {
        int r = rbase + i; ri[i] = r < 0 ? -r : (r > 511 ? 1022 - r : r);
        int c = cbase + i; ci[i] = c < 0 ? -c : (c > 511 ? 1022 - c : c);
    }
    const bool topE = (oh == 0), leftE = (ow == 0);

    float acc[8];
    #pragma unroll
    for (int o = 0; o < 8; ++o) acc[o] = bs[o];

    #pragma unroll
    for (int c = 0; c < 3; ++c) {
        const float* ip = I1 + ((size_t)b * 3 + c) * HW;
        float p[5][5];
        #pragma unroll
        for (int i = 0; i < 5; ++i) {
            const float* rp = ip + ri[i] * WW;
            #pragma unroll
            for (int j = 0; j < 5; ++j) p[i][j] = rp[ci[j]];
        }
        float hs[5][3];
        #pragma unroll
        for (int i = 0; i < 5; ++i)
            #pragma unroll
            for (int j = 0; j < 3; ++j)
                hs[i][j] = kx0 * (p[i][j] + p[i][j + 2]) + kx1 * p[i][j + 1];
        float w2[3][3];
        #pragma unroll
        for (int i = 0; i < 3; ++i)
            #pragma unroll
            for (int j = 0; j < 3; ++j) {
                float bl = g * (ky0 * (hs[i][j] + hs[i + 2][j]) + ky1 * hs[i + 1][j]);
                float val = bl + sg * (p[i + 1][j + 1] - bl);
                w2[i][j] = fminf(fmaxf(val, 1e-5f), 1.0f);
            }
        float* op = I2 + ((size_t)b * 3 + c) * HW + (2 * oh) * WW + 2 * ow;
        float2 w0v; w0v.x = w2[1][1]; w0v.y = w2[1][2];
        float2 w1v; w1v.x = w2[2][1]; w1v.y = w2[2][2];
        *(float2*)op        = w0v;
        *(float2*)(op + WW) = w1v;
        if (topE)  { w2[0][0] = 0.f; w2[0][1] = 0.f; w2[0][2] = 0.f; }
        if (leftE) { w2[0][0] = 0.f; w2[1][0] = 0.f; w2[2][0] = 0.f; }
        #pragma unroll
        for (int o = 0; o < 8; ++o) {
            const float* wr = wt + (o * 3 + c) * 9;          // uniform -> s_load
            acc[o] += w2[0][0] * wr[0] + w2[0][1] * wr[1] + w2[0][2] * wr[2]
                    + w2[1][0] * wr[3] + w2[1][1] * wr[4] + w2[1][2] * wr[5]
                    + w2[2][0] * wr[6] + w2[2][1] * wr[7] + w2[2][2] * wr[8];
        }
    }
    #pragma unroll
    for (int o = 0; o < 8; ++o)
        out[(b * 8 + o) * 65536 + sp] = gelu_exact(acc[o] * BN_MUL);
}

// --- fused attention (K,V folded) --- [round 6 verbatim]
__global__ __launch_bounds__(1024) void attn_kernel(
    const float* __restrict__ dx, const float* __restrict__ q,
    const float* __restrict__ kw, const float* __restrict__ kb,
    const float* __restrict__ vw, const float* __restrict__ vb,
    const float* __restrict__ pw, const float* __restrict__ pb,
    const float* __restrict__ dw, const float* __restrict__ db,
    float* __restrict__ outv, int T)
{
    __shared__ float qk[DIMC];
    __shared__ float red[1024];
    __shared__ float sc[NTOK];
    __shared__ float uN[DIMC];
    __shared__ float osh[DIMC];
    __shared__ float psh[DIMC];
    __shared__ float qkb_s;
    const int tid = threadIdx.x;
    const int bt  = blockIdx.x;
    const int b = bt / T, t = bt - b * T;
    const float* qt = q + t * DIMC;

    if (tid < DIMC) {
        float s = 0.f;
        #pragma unroll
        for (int c = 0; c < DIMC; ++c) s += qt[c] * kw[c * DIMC + tid];
        qk[tid] = s;
    }
    if (tid == 1023) {
        float s = 0.f;
        #pragma unroll
        for (int c = 0; c < DIMC; ++c) s += qt[c] * kb[c];
        qkb_s = s;
    }
    __syncthreads();

    const float* dp = dx + (size_t)(b * DIMC) * NTOK;
    float s = qkb_s;
    #pragma unroll
    for (int c = 0; c < DIMC; ++c) s += qk[c] * dp[c * NTOK + tid];
    s *= 0.125f;

    red[tid] = s;
    __syncthreads();
    for (int off = 512; off > 0; off >>= 1) {
        if (tid < off) red[tid] = fmaxf(red[tid], red[tid + off]);
        __syncthreads();
    }
    float m = red[0];
    __syncthreads();

    float e = __expf(s - m);
    sc[tid] = e;
    red[tid] = e;
    __syncthreads();
    for (int off = 512; off > 0; off >>= 1) {
        if (tid < off) red[tid] += red[tid + off];
        __syncthreads();
    }
    float Ssum = red[0];
    __syncthreads();

    const int c  = tid & 63, qq = tid >> 6;
    float part = 0.f;
    const float* dr = dp + c * NTOK + qq * 64;
    const float* sr = sc + qq * 64;
    #pragma unroll
    for (int n = 0; n < 64; ++n) part += sr[n] * dr[n];
    red[tid] = part;
    __syncthreads();
    if (tid < DIMC) {
        float u = 0.f;
        #pragma unroll
        for (int k = 0; k < 16; ++k) u += red[tid + k * 64];
        uN[tid] = u / Ssum;
    }
    __syncthreads();
    if (tid < DIMC) {
        float o = vb[tid];
        const float* vr = vw + tid * DIMC;
        #pragma unroll
        for (int cc = 0; cc < DIMC; ++cc) o += vr[cc] * uN[cc];
        osh[tid] = o;
    }
    __syncthreads();
    if (tid < DIMC) {
        float p = pb[tid];
        const float* pr = pw + tid * DIMC;
        #pragma unroll
        for (int cc = 0; cc < DIMC; ++cc) p += pr[cc] * osh[cc];
        psh[tid] = p;
    }
    __syncthreads();
    if (tid == 0) {
        float r = db[0];
        #pragma unroll
        for (int cc = 0; cc < DIMC; ++cc) r += psh[cc] * dw[cc];
        outv[bt] = r;
    }
}

// --- chunked sum of I2^dist per (b,c) --- [exp2/log2 fold]
__global__ __launch_bounds__(256) void wb_reduce_kernel(const float* __restrict__ I2,
                                                        const float* __restrict__ attno,
                                                        float* __restrict__ part)
{
    __shared__ float red[256];
    const int bc = blockIdx.y;                 // b*3 + c
    const int b  = bc / 3;
    float d = attno[b * 10 + 9];
    d = fmaxf(d, 0.f) + 1.0f;
    constexpr int CHUNK = HW / WBCH;           // 8192 px
    const float4* base = (const float4*)(I2 + (size_t)bc * HW + blockIdx.x * CHUNK);
    float l = 0.f;
    #pragma unroll
    for (int i = threadIdx.x, it = 0; it < CHUNK / 4 / 256; ++it, i += 256) {
        float4 v = base[i];
        l += exp2f(d * __log2f(v.x)) + exp2f(d * __log2f(v.y))
           + exp2f(d * __log2f(v.z)) + exp2f(d * __log2f(v.w));
    }
    red[threadIdx.x] = l;
    __syncthreads();
    for (int off = 128; off > 0; off >>= 1) {
        if (threadIdx.x < off) red[threadIdx.x] += red[threadIdx.x + off];
        __syncthreads();
    }
    if (threadIdx.x == 0) part[bc * WBCH + blockIdx.x] = red[0];
}

// --- per-batch WB scale + NILUT w1..w3 f16 pre-conversion (256 thr) ---
__global__ void wb_finalize_kernel(const float* __restrict__ part,
                                   const float* __restrict__ attno,
                                   float* __restrict__ wbsc,
                                   const float* __restrict__ w1,
                                   const float* __restrict__ w2,
                                   const float* __restrict__ w3,
                                   _Float16* __restrict__ whf)
{
    const int t = threadIdx.x;
    // pre-convert the three 32x32 NILUT weight matrices to f16 (RTN, same
    // rounding as the previous per-pixel (_Float16) casts -> bit-identical)
    for (int i = t; i < 1024; i += 256) {
        whf[i]        = (_Float16)w1[i];
        whf[1024 + i] = (_Float16)w2[i];
        whf[2048 + i] = (_Float16)w3[i];
    }
    if (t < BB) {
        const int b = t;
        float d = attno[b * 10 + 9];
        d = fmaxf(d, 0.f) + 1.0f;
        float inv = 1.0f / d;
        float s[3];
        #pragma unroll
        for (int c = 0; c < 3; ++c) {
            float t0 = 0.f;
            const float* pp = part + (b * 3 + c) * WBCH;
            #pragma unroll
            for (int k = 0; k < WBCH; ++k) t0 += pp[k];
            s[c] = t0;
        }
        float avg = powf((s[0] + s[1] + s[2]) / (3.0f * (float)HW), inv);
        #pragma unroll
        for (int c = 0; c < 3; ++c)
            wbsc[b * 4 + c] = avg / powf(s[c] / (float)HW, inv);
    }
}

// --- fused WB + CCM + NILUT: layers 2-4 on MFMA f16, v3 ---
//  * tanh: exp2 fold + Montgomery batch-rcp over each MFMA quad
//    (1 v_rcp per 4 tanh; clamp z<=30 keeps products finite)
//  * wave-local lgkmcnt waits (no block barriers), ROW=40, preconverted whf
__global__ void __launch_bounds__(256) final_kernel(
    float* __restrict__ io,
    const float* __restrict__ wbsc, const float* __restrict__ attno,
    const _Float16* __restrict__ whf,
    const float* __restrict__ w0, const float* __restrict__ b0,
    const float* __restrict__ b1, const float* __restrict__ b2,
    const float* __restrict__ b3,
    const float* __restrict__ w4, const float* __restrict__ b4)
{
    constexpr int ROW = 40;                       // f16 per px row (80 B)
    __shared__ __align__(16) _Float16 LDS[4][64 * ROW];   // 20480 B
    const int tid  = threadIdx.x;
    const int wv   = tid >> 6;
    const int lane = tid & 63;
    const int nn   = lane & 15;
    const int quad = lane >> 4;
    _Float16* Wl = LDS[wv];

    const int b   = blockIdx.x >> 10;             // 1024 blocks per image
    const int pix = (blockIdx.x * 256 + tid) & (HW - 1);
    float* base = io + b * 3 * HW + pix;

    const float s0 = wbsc[b * 4 + 0], s1 = wbsc[b * 4 + 1], s2 = wbsc[b * 4 + 2];
    float v0 = base[0] * s0;
    float v1 = base[HW] * s1;
    float v2 = base[2 * HW] * s2;
    const float* o2p = attno + b * 10;            // block-uniform -> scalar
    float I4[3];
    #pragma unroll
    for (int d = 0; d < 3; ++d) {
        float m0 = 0.1f * o2p[d * 3]     + (d == 0 ? 1.f : 0.f);
        float m1 = 0.1f * o2p[d * 3 + 1] + (d == 1 ? 1.f : 0.f);
        float m2 = 0.1f * o2p[d * 3 + 2] + (d == 2 ? 1.f : 0.f);
        I4[d] = fminf(fmaxf(m0 * v0 + m1 * v1 + m2 * v2, 1e-5f), 1.0f);
    }

    #pragma unroll
    for (int j = 0; j < 32; j += 2) {
        float a0 = b0[j]   + w0[j*3]     * I4[0] + w0[j*3+1]     * I4[1] + w0[j*3+2]     * I4[2];
        float a1 = b0[j+1] + w0[(j+1)*3] * I4[0] + w0[(j+1)*3+1] * I4[1] + w0[(j+1)*3+2] * I4[2];
        f16x2 p;
        p[0] = (_Float16)fmaxf(a0, 0.f);
        p[1] = (_Float16)fmaxf(a1, 0.f);
        *(f16x2*)&Wl[lane * ROW + j] = p;
    }

    // weight fragments, pre-converted f16 (one 16B load each)
    f16x8 wf[3][2];
    float bv[3][2];
    const float* bls[3] = { b1, b2, b3 };
    #pragma unroll
    for (int L = 0; L < 3; ++L) {
        #pragma unroll
        for (int h = 0; h < 2; ++h) {
            wf[L][h] = *(const f16x8*)&whf[L * 1024 + (16 * h + nn) * 32 + quad * 8];
            bv[L][h] = bls[L][16 * h + nn];
        }
    }
    // layer-0 stores are wave-local: drain LDS queue instead of block barrier
    asm volatile("s_waitcnt lgkmcnt(0)" ::: "memory");
    __builtin_amdgcn_sched_barrier(0);

    #pragma unroll
    for (int L = 0; L < 3; ++L) {
        f16x8 af[4];
        #pragma unroll
        for (int t = 0; t < 4; ++t)
            af[t] = *(const f16x8*)&Wl[(16 * t + nn) * ROW + quad * 8];
        // af in regs before we overwrite the same region (wave-local WAR)
        asm volatile("s_waitcnt lgkmcnt(0)" ::: "memory");
        __builtin_amdgcn_sched_barrier(0);
        #pragma unroll
        for (int h = 0; h < 2; ++h) {
            f32x4 cb;
            cb[0] = cb[1] = cb[2] = cb[3] = bv[L][h];
            #pragma unroll
            for (int t = 0; t < 4; ++t) {
                f32x4 d = __builtin_amdgcn_mfma_f32_16x16x32_f16(af[t], wf[L][h], cb, 0, 0, 0);
                // tanh(d) = 1 - 2/(exp2(d*2*log2e)+1), batch-rcp over the quad
                float a0 = exp2f(fminf(d[0] * 2.8853900817779268f, 30.0f)) + 1.0f;
                float a1 = exp2f(fminf(d[1] * 2.8853900817779268f, 30.0f)) + 1.0f;
                float a2 = exp2f(fminf(d[2] * 2.8853900817779268f, 30.0f)) + 1.0f;
                float a3 = exp2f(fminf(d[3] * 2.8853900817779268f, 30.0f)) + 1.0f;
                float p01 = a0 * a1, p23 = a2 * a3;
                float R   = __builtin_amdgcn_rcpf(p01 * p23);
                float r01 = R * p23, r23 = R * p01;   // 1/(a0a1), 1/(a2a3)
                float iv0 = r01 * a1, iv1 = r01 * a0;
                float iv2 = r23 * a3, iv3 = r23 * a2;
                Wl[(16 * t + quad * 4 + 0) * ROW + 16 * h + nn] = (_Float16)fmaf(-2.0f, iv0, 1.0f);
                Wl[(16 * t + quad * 4 + 1) * ROW + 16 * h + nn] = (_Float16)fmaf(-2.0f, iv1, 1.0f);
                Wl[(16 * t + quad * 4 + 2) * ROW + 16 * h + nn] = (_Float16)fmaf(-2.0f, iv2, 1.0f);
                Wl[(16 * t + quad * 4 + 3) * ROW + 16 * h + nn] = (_Float16)fmaf(-2.0f, iv3, 1.0f);
            }
        }
        // stores visible before next layer's reads (wave-local RAW)
        asm volatile("s_waitcnt lgkmcnt(0)" ::: "memory");
        __builtin_amdgcn_sched_barrier(0);
    }

    float h4[32];
    #pragma unroll
    for (int g = 0; g < 4; ++g) {
        f16x8 rv = *(const f16x8*)&Wl[lane * ROW + g * 8];
        #pragma unroll
        for (int i = 0; i < 8; ++i) h4[g * 8 + i] = (float)rv[i];
    }
    #pragma unroll
    for (int d = 0; d < 3; ++d) {
        float a = b4[d];
        const float* wr = w4 + d * 32;            // uniform -> s_load
        #pragma unroll
        for (int k = 0; k < 32; ++k) a += h4[k] * wr[k];
        a += I4[d];
        base[d * HW] = fminf(fmaxf(a, 0.f), 1.0f);
    }
}

extern "C" void kernel_launch(void* const* d_in, const int* in_sizes, int n_in,
                              void* d_out, int out_size, void* d_ws, size_t ws_size,
                              hipStream_t stream)
{
    const float* I1      = (const float*)d_in[0];
    const float* kp_q    = (const float*)d_in[1];
    const float* kp_c1w  = (const float*)d_in[2];  const float* kp_c1b = (const float*)d_in[3];
    const float* kp_c2w  = (const float*)d_in[4];  const float* kp_c2b = (const float*)d_in[5];
    const float* kp_c3w  = (const float*)d_in[6];  const float* kp_c3b = (const float*)d_in[7];
    const float* kp_c4w  = (const float*)d_in[8];  const float* kp_c4b = (const float*)d_in[9];
    const float* kp_kw   = (const float*)d_in[10]; const float* kp_vw  = (const float*)d_in[11];
    const float* kp_pw   = (const float*)d_in[12]; const float* kp_dw  = (const float*)d_in[13];
    const float* kp_kb   = (const float*)d_in[14]; const float* kp_vb  = (const float*)d_in[15];
    const float* kp_pb   = (const float*)d_in[16]; const float* kp_db  = (const float*)d_in[17];
    const float* mp_q    = (const float*)d_in[18];
    const float* mp_c1w  = (const float*)d_in[19]; const float* mp_c1b = (const float*)d_in[20];
    const float* mp_c2w  = (const float*)d_in[21]; const float* mp_c2b = (const float*)d_in[22];
    const float* mp_c3w  = (const float*)d_in[23]; const float* mp_c3b = (const float*)d_in[24];
    const float* mp_c4w  = (const float*)d_in[25]; const float* mp_c4b = (const float*)d_in[26];
    const float* mp_kw   = (const float*)d_in[27]; const float* mp_vw  = (const float*)d_in[28];
    const float* mp_pw   = (const float*)d_in[29]; const float* mp_dw  = (const float*)d_in[30];
    const float* mp_kb   = (const float*)d_in[31]; const float* mp_vb  = (const float*)d_in[32];
    const float* mp_pb   = (const float*)d_in[33]; const float* mp_db  = (const float*)d_in[34];
    const float* gainb   = (const float*)d_in[35];
    const float* lw0 = (const float*)d_in[36]; const float* lb0 = (const float*)d_in[37];
    const float* lw1 = (const float*)d_in[38]; const float* lb1 = (const float*)d_in[39];
    const float* lw2 = (const float*)d_in[40]; const float* lb2 = (const float*)d_in[41];
    const float* lw3 = (const float*)d_in[42]; const float* lb3 = (const float*)d_in[43];
    const float* lw4 = (const float*)d_in[44]; const float* lb4 = (const float*)d_in[45];

    float* ws    = (float*)d_ws;
    float* ds1   = ws;                          // 8*8*256*256   = 4194304
    float* ds2   = ds1 + 8 * 8 * 256 * 256;     // 8*16*128*128  = 2097152
    float* ds3   = ds2 + 8 * 16 * 128 * 128;    // 8*32*64*64    = 1048576
    float* ds4   = ds3 + 8 * 32 * 64 * 64;      // 8*64*32*32    = 524288
    float* attno = ds4 + 8 * 64 * 32 * 32;      // 128 (kp: b*4+t / mp: b*10+t)
    float* part  = attno + 128;                 // 24 * WBCH
    float* wbsc  = part + 24 * WBCH;            // 32
    float* I2    = (float*)d_out;               // I2 lives in d_out
    // f16 NILUT weights live in the (dead-by-then) ds1 region: 3072 f16
    _Float16* whf = (_Float16*)ds1;

    // --- Kernel_Predictor --- [round 6 configs]
    conv_s2<3, 512, 8, true ><<<dim3(256, 1, BB), 256, 0, stream>>>(I1,  kp_c1w, kp_c1b, ds1);
    conv_s2<8, 256, 8, true ><<<dim3(64,  2, BB), 256, 0, stream>>>(ds1, kp_c2w, kp_c2b, ds2);
    conv_s2<16, 128, 4, true><<<dim3(16,  8, BB), 256, 0, stream>>>(ds2, kp_c3w, kp_c3b, ds3);
    conv_s2<32, 64, 4, false><<<dim3(4,  16, BB), 256, 0, stream>>>(ds3, kp_c4w, kp_c4b, ds4);
    attn_kernel<<<BB * 4, 1024, 0, stream>>>(ds4, kp_q, kp_kw, kp_kb, kp_vw, kp_vb,
                                             kp_pw, kp_pb, kp_dw, kp_db, attno, 4);

    // --- denoise fused with conv1_mp: writes I2 (d_out) + ds1 ---
    denoise_conv1_kernel<<<dim3(256, 1, BB), 256, 0, stream>>>(I1, attno, gainb,
                                                               mp_c1w, mp_c1b, I2, ds1);

    // --- rest of Matrix_Predictor ---
    conv_s2<8, 256, 8, true ><<<dim3(64,  2, BB), 256, 0, stream>>>(ds1, mp_c2w, mp_c2b, ds2);
    conv_s2<16, 128, 4, true><<<dim3(16,  8, BB), 256, 0, stream>>>(ds2, mp_c3w, mp_c3b, ds3);
    conv_s2<32, 64, 4, false><<<dim3(4,  16, BB), 256, 0, stream>>>(ds3, mp_c4w, mp_c4b, ds4);
    attn_kernel<<<BB * 10, 1024, 0, stream>>>(ds4, mp_q, mp_kw, mp_kb, mp_vw, mp_vb,
                                              mp_pw, mp_pb, mp_dw, mp_db, attno, 10);

    // --- shades-of-gray reduction ---
    wb_reduce_kernel<<<dim3(WBCH, 24), 256, 0, stream>>>(I2, attno, part);
    wb_finalize_kernel<<<1, 256, 0, stream>>>(part, attno, wbsc, lw1, lw2, lw3, whf);

    // --- fused WB + CCM + NILUT (in-place on d_out) ---
    final_kernel<<<BB * HW / 256, 256, 0, stream>>>(I2, wbsc, attno, whf,
        lw0, lb0, lb1, lb2, lb3, lw4, lb4);
}

// Round 3
// 423.013 us; speedup vs baseline: 1.0742x; 1.0742x over previous
//
#include <hip/hip_runtime.h>
#include <math.h>

// ---------------------------------------------------------------------------
// Input_level_Adapeter pipeline, round 13 (Montgomery redo, native exp2):
//  - r12 post-mortem: library exp2f is NOT v_exp_f32 (multi-inst precise
//    sequence) -> +2000 cy/wave. Trans ops measured ~16cy and DO occupy the
//    VALU issue pipe -> rcp elimination is worth 16cy each.
//  - final_kernel v4 = round-11 base (83 us, verified) + batch-rcp tanh:
//      * __builtin_amdgcn_exp2f(d*2*log2e) — guaranteed single v_exp_f32
//      * ONE v_rcp per MFMA quad (Montgomery), no clamp (|d|<=6.5 bound)
//      * predicted -720 cy/wave (-13%)
//  - wb_reduce reverted to native __expf/__logf (r11 form).
//  - conv_s2 / denoise_conv1 / attn / wb_finalize = round 11 verbatim.
// d_out doubles as the I2 buffer.
// ---------------------------------------------------------------------------

#define BN_MUL 0.9999950000374997f   // 1/sqrt(1+1e-5)

static constexpr int BB   = 8;
static constexpr int HH   = 512;
static constexpr int WW   = 512;
static constexpr int HW   = HH * WW;
static constexpr int NTOK = 1024;    // (512/16)^2
static constexpr int DIMC = 64;
static constexpr int WBCH = 32;      // wb_reduce chunks per (b,c)

typedef _Float16 f16x8 __attribute__((ext_vector_type(8)));
typedef _Float16 f16x2 __attribute__((ext_vector_type(2)));
typedef float    f32x4 __attribute__((ext_vector_type(4)));

__device__ __forceinline__ float gelu_exact(float x) {
    return 0.5f * x * (1.0f + erff(x * 0.7071067811865476f));
}

// --- stride-2 3x3 conv + bias + BN (+ optional exact GELU), zero padding ---
// [round 6 verbatim] grid: (Hout*Wout/256, Cout/OCT, B).
template<int Cin, int Hin, int OCT, bool GELU>
__global__ __launch_bounds__(256) void conv_s2(const float* __restrict__ in,
                                               const float* __restrict__ wt,
                                               const float* __restrict__ bs,
                                               float* __restrict__ out)
{
    constexpr int Win  = Hin, Hout = Hin / 2, Wout = Hin / 2;
    constexpr int WSH  = (Wout == 256) ? 8 : (Wout == 128) ? 7 : (Wout == 64) ? 6 : 5;
    constexpr int PLANE = Hout * Wout;

    const int sp  = blockIdx.x * 256 + threadIdx.x;
    const int ow  = sp & (Wout - 1);
    const int oh  = sp >> WSH;
    const int oc0 = blockIdx.y * OCT;
    const int b   = blockIdx.z;
    const int Cout = (int)gridDim.y * OCT;

    float acc[OCT];
    #pragma unroll
    for (int o = 0; o < OCT; ++o) acc[o] = bs[oc0 + o];

    const int ih0 = oh * 2 - 1, iw0 = ow * 2 - 1;
    const float fh0 = (ih0 >= 0) ? 1.f : 0.f;
    const float fw0 = (iw0 >= 0) ? 1.f : 0.f;
    const int r0 = (ih0 >= 0) ? ih0 : 0;
    const int cc0 = (iw0 >= 0) ? iw0 : 0;

    const float* ip = in + (size_t)(b * Cin) * Hin * Win;
    #pragma unroll
    for (int ic = 0; ic < Cin; ++ic) {
        const float* pl = ip + ic * Hin * Win;
        const float* p0 = pl + r0 * Win;
        const float* p1 = pl + (ih0 + 1) * Win;
        const float* p2 = pl + (ih0 + 2) * Win;
        float  v00 = p0[cc0] * (fh0 * fw0);
        float2 va  = *(const float2*)(p0 + iw0 + 1);
        float  v01 = va.x * fh0, v02 = va.y * fh0;
        float  v10 = p1[cc0] * fw0;
        float2 vb  = *(const float2*)(p1 + iw0 + 1);
        float  v20 = p2[cc0] * fw0;
        float2 vc  = *(const float2*)(p2 + iw0 + 1);
        #pragma unroll
        for (int o = 0; o < OCT; ++o) {
            const float* wr = wt + ((oc0 + o) * Cin + ic) * 9;   // uniform -> s_load
            acc[o] += v00 * wr[0] + v01 * wr[1] + v02 * wr[2]
                    + v10 * wr[3] + vb.x * wr[4] + vb.y * wr[5]
                    + v20 * wr[6] + vc.x * wr[7] + vc.y * wr[8];
        }
    }
    #pragma unroll
    for (int o = 0; o < OCT; ++o) {
        float a = acc[o] * BN_MUL;
        if (GELU) a = gelu_exact(a);
        out[(size_t)(b * Cout + oc0 + o) * PLANE + sp] = a;
    }
}

// --- fused denoise + conv1_mp --- [round 6 verbatim]
__global__ __launch_bounds__(256) void denoise_conv1_kernel(
    const float* __restrict__ I1, const float* __restrict__ attno,
    const float* __restrict__ gain_base,
    const float* __restrict__ wt, const float* __restrict__ bs,
    float* __restrict__ I2, float* __restrict__ out)
{
    const int sp = blockIdx.x * 256 + threadIdx.x;
    const int ow = sp & 255;
    const int oh = sp >> 8;
    const int b  = blockIdx.z;

    const float o0 = attno[b * 4 + 0], o1 = attno[b * 4 + 1];
    const float o2 = attno[b * 4 + 2], o3 = attno[b * 4 + 3];
    const float r1 = 0.1f * o0 + 3.0f;
    const float r2 = 0.1f * o1 + 2.0f;
    const float g  = o2 + gain_base[0];
    const float sg = 1.0f / (1.0f + __expf(-o3));
    const float ex = __expf(-0.5f / (r1 * r1));
    const float nx = 1.0f / (2.0f * ex + 1.0f);
    const float ey = __expf(-0.5f / (r2 * r2));
    const float ny = 1.0f / (2.0f * ey + 1.0f);
    const float kx0 = ex * nx, kx1 = nx;
    const float ky0 = ey * ny, ky1 = ny;

    const int rbase = 2 * oh - 2, cbase = 2 * ow - 2;
    int ri[5], ci[5];
    #pragma unroll
    for (int i = 0; i < 5; ++i) {
        int r = rbase + i; ri[i] = r < 0 ? -r : (r > 511 ? 1022 - r : r);
        int c = cbase + i; ci[i] = c < 0 ? -c : (c > 511 ? 1022 - c : c);
    }
    const bool topE = (oh == 0), leftE = (ow == 0);

    float acc[8];
    #pragma unroll
    for (int o = 0; o < 8; ++o) acc[o] = bs[o];

    #pragma unroll
    for (int c = 0; c < 3; ++c) {
        const float* ip = I1 + ((size_t)b * 3 + c) * HW;
        float p[5][5];
        #pragma unroll
        for (int i = 0; i < 5; ++i) {
            const float* rp = ip + ri[i] * WW;
            #pragma unroll
            for (int j = 0; j < 5; ++j) p[i][j] = rp[ci[j]];
        }
        float hs[5][3];
        #pragma unroll
        for (int i = 0; i < 5; ++i)
            #pragma unroll
            for (int j = 0; j < 3; ++j)
                hs[i][j] = kx0 * (p[i][j] + p[i][j + 2]) + kx1 * p[i][j + 1];
        float w2[3][3];
        #pragma unroll
        for (int i = 0; i < 3; ++i)
            #pragma unroll
            for (int j = 0; j < 3; ++j) {
                float bl = g * (ky0 * (hs[i][j] + hs[i + 2][j]) + ky1 * hs[i + 1][j]);
                float val = bl + sg * (p[i + 1][j + 1] - bl);
                w2[i][j] = fminf(fmaxf(val, 1e-5f), 1.0f);
            }
        float* op = I2 + ((size_t)b * 3 + c) * HW + (2 * oh) * WW + 2 * ow;
        float2 w0v; w0v.x = w2[1][1]; w0v.y = w2[1][2];
        float2 w1v; w1v.x = w2[2][1]; w1v.y = w2[2][2];
        *(float2*)op        = w0v;
        *(float2*)(op + WW) = w1v;
        if (topE)  { w2[0][0] = 0.f; w2[0][1] = 0.f; w2[0][2] = 0.f; }
        if (leftE) { w2[0][0] = 0.f; w2[1][0] = 0.f; w2[2][0] = 0.f; }
        #pragma unroll
        for (int o = 0; o < 8; ++o) {
            const float* wr = wt + (o * 3 + c) * 9;          // uniform -> s_load
            acc[o] += w2[0][0] * wr[0] + w2[0][1] * wr[1] + w2[0][2] * wr[2]
                    + w2[1][0] * wr[3] + w2[1][1] * wr[4] + w2[1][2] * wr[5]
                    + w2[2][0] * wr[6] + w2[2][1] * wr[7] + w2[2][2] * wr[8];
        }
    }
    #pragma unroll
    for (int o = 0; o < 8; ++o)
        out[(b * 8 + o) * 65536 + sp] = gelu_exact(acc[o] * BN_MUL);
}

// --- fused attention (K,V folded) --- [round 6 verbatim]
__global__ __launch_bounds__(1024) void attn_kernel(
    const float* __restrict__ dx, const float* __restrict__ q,
    const float* __restrict__ kw, const float* __restrict__ kb,
    const float* __restrict__ vw, const float* __restrict__ vb,
    const float* __restrict__ pw, const float* __restrict__ pb,
    const float* __restrict__ dw, const float* __restrict__ db,
    float* __restrict__ outv, int T)
{
    __shared__ float qk[DIMC];
    __shared__ float red[1024];
    __shared__ float sc[NTOK];
    __shared__ float uN[DIMC];
    __shared__ float osh[DIMC];
    __shared__ float psh[DIMC];
    __shared__ float qkb_s;
    const int tid = threadIdx.x;
    const int bt  = blockIdx.x;
    const int b = bt / T, t = bt - b * T;
    const float* qt = q + t * DIMC;

    if (tid < DIMC) {
        float s = 0.f;
        #pragma unroll
        for (int c = 0; c < DIMC; ++c) s += qt[c] * kw[c * DIMC + tid];
        qk[tid] = s;
    }
    if (tid == 1023) {
        float s = 0.f;
        #pragma unroll
        for (int c = 0; c < DIMC; ++c) s += qt[c] * kb[c];
        qkb_s = s;
    }
    __syncthreads();

    const float* dp = dx + (size_t)(b * DIMC) * NTOK;
    float s = qkb_s;
    #pragma unroll
    for (int c = 0; c < DIMC; ++c) s += qk[c] * dp[c * NTOK + tid];
    s *= 0.125f;

    red[tid] = s;
    __syncthreads();
    for (int off = 512; off > 0; off >>= 1) {
        if (tid < off) red[tid] = fmaxf(red[tid], red[tid + off]);
        __syncthreads();
    }
    float m = red[0];
    __syncthreads();

    float e = __expf(s - m);
    sc[tid] = e;
    red[tid] = e;
    __syncthreads();
    for (int off = 512; off > 0; off >>= 1) {
        if (tid < off) red[tid] += red[tid + off];
        __syncthreads();
    }
    float Ssum = red[0];
    __syncthreads();

    const int c  = tid & 63, qq = tid >> 6;
    float part = 0.f;
    const float* dr = dp + c * NTOK + qq * 64;
    const float* sr = sc + qq * 64;
    #pragma unroll
    for (int n = 0; n < 64; ++n) part += sr[n] * dr[n];
    red[tid] = part;
    __syncthreads();
    if (tid < DIMC) {
        float u = 0.f;
        #pragma unroll
        for (int k = 0; k < 16; ++k) u += red[tid + k * 64];
        uN[tid] = u / Ssum;
    }
    __syncthreads();
    if (tid < DIMC) {
        float o = vb[tid];
        const float* vr = vw + tid * DIMC;
        #pragma unroll
        for (int cc = 0; cc < DIMC; ++cc) o += vr[cc] * uN[cc];
        osh[tid] = o;
    }
    __syncthreads();
    if (tid < DIMC) {
        float p = pb[tid];
        const float* pr = pw + tid * DIMC;
        #pragma unroll
        for (int cc = 0; cc < DIMC; ++cc) p += pr[cc] * osh[cc];
        psh[tid] = p;
    }
    __syncthreads();
    if (tid == 0) {
        float r = db[0];
        #pragma unroll
        for (int cc = 0; cc < DIMC; ++cc) r += psh[cc] * dw[cc];
        outv[bt] = r;
    }
}

// --- chunked sum of I2^dist per (b,c) --- [round 11 verbatim, native trans]
__global__ __launch_bounds__(256) void wb_reduce_kernel(const float* __restrict__ I2,
                                                        const float* __restrict__ attno,
                                                        float* __restrict__ part)
{
    __shared__ float red[256];
    const int bc = blockIdx.y;                 // b*3 + c
    const int b  = bc / 3;
    float d = attno[b * 10 + 9];
    d = fmaxf(d, 0.f) + 1.0f;
    constexpr int CHUNK = HW / WBCH;           // 8192 px
    const float4* base = (const float4*)(I2 + (size_t)bc * HW + blockIdx.x * CHUNK);
    float l = 0.f;
    #pragma unroll
    for (int i = threadIdx.x, it = 0; it < CHUNK / 4 / 256; ++it, i += 256) {
        float4 v = base[i];
        l += __expf(d * __logf(v.x)) + __expf(d * __logf(v.y))
           + __expf(d * __logf(v.z)) + __expf(d * __logf(v.w));
    }
    red[threadIdx.x] = l;
    __syncthreads();
    for (int off = 128; off > 0; off >>= 1) {
        if (threadIdx.x < off) red[threadIdx.x] += red[threadIdx.x + off];
        __syncthreads();
    }
    if (threadIdx.x == 0) part[bc * WBCH + blockIdx.x] = red[0];
}

// --- per-batch WB scale + NILUT w1..w3 f16 pre-conversion (256 thr) ---
__global__ void wb_finalize_kernel(const float* __restrict__ part,
                                   const float* __restrict__ attno,
                                   float* __restrict__ wbsc,
                                   const float* __restrict__ w1,
                                   const float* __restrict__ w2,
                                   const float* __restrict__ w3,
                                   _Float16* __restrict__ whf)
{
    const int t = threadIdx.x;
    // pre-convert the three 32x32 NILUT weight matrices to f16 (RTN, same
    // rounding as the previous per-pixel (_Float16) casts -> bit-identical)
    for (int i = t; i < 1024; i += 256) {
        whf[i]        = (_Float16)w1[i];
        whf[1024 + i] = (_Float16)w2[i];
        whf[2048 + i] = (_Float16)w3[i];
    }
    if (t < BB) {
        const int b = t;
        float d = attno[b * 10 + 9];
        d = fmaxf(d, 0.f) + 1.0f;
        float inv = 1.0f / d;
        float s[3];
        #pragma unroll
        for (int c = 0; c < 3; ++c) {
            float t0 = 0.f;
            const float* pp = part + (b * 3 + c) * WBCH;
            #pragma unroll
            for (int k = 0; k < WBCH; ++k) t0 += pp[k];
            s[c] = t0;
        }
        float avg = powf((s[0] + s[1] + s[2]) / (3.0f * (float)HW), inv);
        #pragma unroll
        for (int c = 0; c < 3; ++c)
            wbsc[b * 4 + c] = avg / powf(s[c] / (float)HW, inv);
    }
}

// --- fused WB + CCM + NILUT: layers 2-4 on MFMA f16, v4 ---
//  * round-11 structure (wave-local waits, ROW=40, preconverted whf)
//  * tanh: native v_exp_f32 (exp2 intrinsic) + Montgomery batch-rcp per quad
__global__ void __launch_bounds__(256) final_kernel(
    float* __restrict__ io,
    const float* __restrict__ wbsc, const float* __restrict__ attno,
    const _Float16* __restrict__ whf,
    const float* __restrict__ w0, const float* __restrict__ b0,
    const float* __restrict__ b1, const float* __restrict__ b2,
    const float* __restrict__ b3,
    const float* __restrict__ w4, const float* __restrict__ b4)
{
    constexpr int ROW = 40;                       // f16 per px row (80 B)
    __shared__ __align__(16) _Float16 LDS[4][64 * ROW];   // 20480 B
    const int tid  = threadIdx.x;
    const int wv   = tid >> 6;
    const int lane = tid & 63;
    const int nn   = lane & 15;
    const int quad = lane >> 4;
    _Float16* Wl = LDS[wv];

    const int b   = blockIdx.x >> 10;             // 1024 blocks per image
    const int pix = (blockIdx.x * 256 + tid) & (HW - 1);
    float* base = io + b * 3 * HW + pix;

    const float s0 = wbsc[b * 4 + 0], s1 = wbsc[b * 4 + 1], s2 = wbsc[b * 4 + 2];
    float v0 = base[0] * s0;
    float v1 = base[HW] * s1;
    float v2 = base[2 * HW] * s2;
    const float* o2p = attno + b * 10;            // block-uniform -> scalar
    float I4[3];
    #pragma unroll
    for (int d = 0; d < 3; ++d) {
        float m0 = 0.1f * o2p[d * 3]     + (d == 0 ? 1.f : 0.f);
        float m1 = 0.1f * o2p[d * 3 + 1] + (d == 1 ? 1.f : 0.f);
        float m2 = 0.1f * o2p[d * 3 + 2] + (d == 2 ? 1.f : 0.f);
        I4[d] = fminf(fmaxf(m0 * v0 + m1 * v1 + m2 * v2, 1e-5f), 1.0f);
    }

    #pragma unroll
    for (int j = 0; j < 32; j += 2) {
        float a0 = b0[j]   + w0[j*3]     * I4[0] + w0[j*3+1]     * I4[1] + w0[j*3+2]     * I4[2];
        float a1 = b0[j+1] + w0[(j+1)*3] * I4[0] + w0[(j+1)*3+1] * I4[1] + w0[(j+1)*3+2] * I4[2];
        f16x2 p;
        p[0] = (_Float16)fmaxf(a0, 0.f);
        p[1] = (_Float16)fmaxf(a1, 0.f);
        *(f16x2*)&Wl[lane * ROW + j] = p;
    }

    // weight fragments, pre-converted f16 (one 16B load each)
    f16x8 wf[3][2];
    float bv[3][2];
    const float* bls[3] = { b1, b2, b3 };
    #pragma unroll
    for (int L = 0; L < 3; ++L) {
        #pragma unroll
        for (int h = 0; h < 2; ++h) {
            wf[L][h] = *(const f16x8*)&whf[L * 1024 + (16 * h + nn) * 32 + quad * 8];
            bv[L][h] = bls[L][16 * h + nn];
        }
    }
    // layer-0 stores are wave-local: drain LDS queue instead of block barrier
    asm volatile("s_waitcnt lgkmcnt(0)" ::: "memory");
    __builtin_amdgcn_sched_barrier(0);

    #pragma unroll
    for (int L = 0; L < 3; ++L) {
        f16x8 af[4];
        #pragma unroll
        for (int t = 0; t < 4; ++t)
            af[t] = *(const f16x8*)&Wl[(16 * t + nn) * ROW + quad * 8];
        // af in regs before we overwrite the same region (wave-local WAR)
        asm volatile("s_waitcnt lgkmcnt(0)" ::: "memory");
        __builtin_amdgcn_sched_barrier(0);
        #pragma unroll
        for (int h = 0; h < 2; ++h) {
            f32x4 cb;
            cb[0] = cb[1] = cb[2] = cb[3] = bv[L][h];
            #pragma unroll
            for (int t = 0; t < 4; ++t) {
                f32x4 d = __builtin_amdgcn_mfma_f32_16x16x32_f16(af[t], wf[L][h], cb, 0, 0, 0);
                // tanh(x) = 1 - 2/(2^(x*2*log2e)+1); ONE v_rcp per quad.
                // |d| <= ~6.5 (32 products of tanh<=1 x 0.2-scale weights)
                // -> no overflow guard needed (v_exp_f32 fine to 2^127).
                float a0 = __builtin_amdgcn_exp2f(d[0] * 2.8853900817779268f) + 1.0f;
                float a1 = __builtin_amdgcn_exp2f(d[1] * 2.8853900817779268f) + 1.0f;
                float a2 = __builtin_amdgcn_exp2f(d[2] * 2.8853900817779268f) + 1.0f;
                float a3 = __builtin_amdgcn_exp2f(d[3] * 2.8853900817779268f) + 1.0f;
                float p01 = a0 * a1, p23 = a2 * a3;
                float R   = __builtin_amdgcn_rcpf(p01 * p23);
                float r01 = R * p23, r23 = R * p01;   // 1/(a0a1), 1/(a2a3)
                Wl[(16 * t + quad * 4 + 0) * ROW + 16 * h + nn] = (_Float16)fmaf(-2.0f, r01 * a1, 1.0f);
                Wl[(16 * t + quad * 4 + 1) * ROW + 16 * h + nn] = (_Float16)fmaf(-2.0f, r01 * a0, 1.0f);
                Wl[(16 * t + quad * 4 + 2) * ROW + 16 * h + nn] = (_Float16)fmaf(-2.0f, r23 * a3, 1.0f);
                Wl[(16 * t + quad * 4 + 3) * ROW + 16 * h + nn] = (_Float16)fmaf(-2.0f, r23 * a2, 1.0f);
            }
        }
        // stores visible before next layer's reads (wave-local RAW)
        asm volatile("s_waitcnt lgkmcnt(0)" ::: "memory");
        __builtin_amdgcn_sched_barrier(0);
    }

    float h4[32];
    #pragma unroll
    for (int g = 0; g < 4; ++g) {
        f16x8 rv = *(const f16x8*)&Wl[lane * ROW + g * 8];
        #pragma unroll
        for (int i = 0; i < 8; ++i) h4[g * 8 + i] = (float)rv[i];
    }
    #pragma unroll
    for (int d = 0; d < 3; ++d) {
        float a = b4[d];
        const float* wr = w4 + d * 32;            // uniform -> s_load
        #pragma unroll
        for (int k = 0; k < 32; ++k) a += h4[k] * wr[k];
        a += I4[d];
        base[d * HW] = fminf(fmaxf(a, 0.f), 1.0f);
    }
}

extern "C" void kernel_launch(void* const* d_in, const int* in_sizes, int n_in,
                              void* d_out, int out_size, void* d_ws, size_t ws_size,
                              hipStream_t stream)
{
    const float* I1      = (const float*)d_in[0];
    const float* kp_q    = (const float*)d_in[1];
    const float* kp_c1w  = (const float*)d_in[2];  const float* kp_c1b = (const float*)d_in[3];
    const float* kp_c2w  = (const float*)d_in[4];  const float* kp_c2b = (const float*)d_in[5];
    const float* kp_c3w  = (const float*)d_in[6];  const float* kp_c3b = (const float*)d_in[7];
    const float* kp_c4w  = (const float*)d_in[8];  const float* kp_c4b = (const float*)d_in[9];
    const float* kp_kw   = (const float*)d_in[10]; const float* kp_vw  = (const float*)d_in[11];
    const float* kp_pw   = (const float*)d_in[12]; const float* kp_dw  = (const float*)d_in[13];
    const float* kp_kb   = (const float*)d_in[14]; const float* kp_vb  = (const float*)d_in[15];
    const float* kp_pb   = (const float*)d_in[16]; const float* kp_db  = (const float*)d_in[17];
    const float* mp_q    = (const float*)d_in[18];
    const float* mp_c1w  = (const float*)d_in[19]; const float* mp_c1b = (const float*)d_in[20];
    const float* mp_c2w  = (const float*)d_in[21]; const float* mp_c2b = (const float*)d_in[22];
    const float* mp_c3w  = (const float*)d_in[23]; const float* mp_c3b = (const float*)d_in[24];
    const float* mp_c4w  = (const float*)d_in[25]; const float* mp_c4b = (const float*)d_in[26];
    const float* mp_kw   = (const float*)d_in[27]; const float* mp_vw  = (const float*)d_in[28];
    const float* mp_pw   = (const float*)d_in[29]; const float* mp_dw  = (const float*)d_in[30];
    const float* mp_kb   = (const float*)d_in[31]; const float* mp_vb  = (const float*)d_in[32];
    const float* mp_pb   = (const float*)d_in[33]; const float* mp_db  = (const float*)d_in[34];
    const float* gainb   = (const float*)d_in[35];
    const float* lw0 = (const float*)d_in[36]; const float* lb0 = (const float*)d_in[37];
    const float* lw1 = (const float*)d_in[38]; const float* lb1 = (const float*)d_in[39];
    const float* lw2 = (const float*)d_in[40]; const float* lb2 = (const float*)d_in[41];
    const float* lw3 = (const float*)d_in[42]; const float* lb3 = (const float*)d_in[43];
    const float* lw4 = (const float*)d_in[44]; const float* lb4 = (const float*)d_in[45];

    float* ws    = (float*)d_ws;
    float* ds1   = ws;                          // 8*8*256*256   = 4194304
    float* ds2   = ds1 + 8 * 8 * 256 * 256;     // 8*16*128*128  = 2097152
    float* ds3   = ds2 + 8 * 16 * 128 * 128;    // 8*32*64*64    = 1048576
    float* ds4   = ds3 + 8 * 32 * 64 * 64;      // 8*64*32*32    = 524288
    float* attno = ds4 + 8 * 64 * 32 * 32;      // 128 (kp: b*4+t / mp: b*10+t)
    float* part  = attno + 128;                 // 24 * WBCH
    float* wbsc  = part + 24 * WBCH;            // 32
    float* I2    = (float*)d_out;               // I2 lives in d_out
    // f16 NILUT weights live in the (dead-by-then) ds1 region: 3072 f16
    _Float16* whf = (_Float16*)ds1;

    // --- Kernel_Predictor --- [round 6 configs]
    conv_s2<3, 512, 8, true ><<<dim3(256, 1, BB), 256, 0, stream>>>(I1,  kp_c1w, kp_c1b, ds1);
    conv_s2<8, 256, 8, true ><<<dim3(64,  2, BB), 256, 0, stream>>>(ds1, kp_c2w, kp_c2b, ds2);
    conv_s2<16, 128, 4, true><<<dim3(16,  8, BB), 256, 0, stream>>>(ds2, kp_c3w, kp_c3b, ds3);
    conv_s2<32, 64, 4, false><<<dim3(4,  16, BB), 256, 0, stream>>>(ds3, kp_c4w, kp_c4b, ds4);
    attn_kernel<<<BB * 4, 1024, 0, stream>>>(ds4, kp_q, kp_kw, kp_kb, kp_vw, kp_vb,
                                             kp_pw, kp_pb, kp_dw, kp_db, attno, 4);

    // --- denoise fused with conv1_mp: writes I2 (d_out) + ds1 ---
    denoise_conv1_kernel<<<dim3(256, 1, BB), 256, 0, stream>>>(I1, attno, gainb,
                                                               mp_c1w, mp_c1b, I2, ds1);

    // --- rest of Matrix_Predictor ---
    conv_s2<8, 256, 8, true ><<<dim3(64,  2, BB), 256, 0, stream>>>(ds1, mp_c2w, mp_c2b, ds2);
    conv_s2<16, 128, 4, true><<<dim3(16,  8, BB), 256, 0, stream>>>(ds2, mp_c3w, mp_c3b, ds3);
    conv_s2<32, 64, 4, false><<<dim3(4,  16, BB), 256, 0, stream>>>(ds3, mp_c4w, mp_c4b, ds4);
    attn_kernel<<<BB * 10, 1024, 0, stream>>>(ds4, mp_q, mp_kw, mp_kb, mp_vw, mp_vb,
                                              mp_pw, mp_pb, mp_dw, mp_db, attno, 10);

    // --- shades-of-gray reduction ---
    wb_reduce_kernel<<<dim3(WBCH, 24), 256, 0, stream>>>(I2, attno, part);
    wb_finalize_kernel<<<1, 256, 0, stream>>>(part, attno, wbsc, lw1, lw2, lw3, whf);

    // --- fused WB + CCM + NILUT (in-place on d_out) ---
    final_kernel<<<BB * HW / 256, 256, 0, stream>>>(I2, wbsc, attno, whf,
        lw0, lb0, lb1, lb2, lb3, lw4, lb4);
}

// Round 4
// 412.470 us; speedup vs baseline: 1.1016x; 1.0256x over previous
//
#include <hip/hip_runtime.h>
#include <math.h>

// ---------------------------------------------------------------------------
// Input_level_Adapeter pipeline, round 14 (attn coalescing pass):
//  - r13 post-mortem: final_kernel is at its issue floor (~82us); the
//    unaccounted ~270us of the 423us pipeline is below final in the top-5.
//    Prime suspect: attn_kernel's PV loop gathers dp with 4KB lane stride
//    (64 cache lines PER LOAD, 64 loads/thread, tiny 32/80-block grids).
//  - attn_kernel v2:
//      * PV = row-major matvec: wave w owns channels 4w..4w+3, lanes iterate
//        tokens -> fully coalesced 256B loads + shfl_xor butterfly reduce
//      * softmax max/sum: wave shuffle butterflies + 16-entry LDS cross-wave
//        (6 barriers total vs 26)
//      * fp32 reassociation only (~1e-6 on attno) -> absmax unchanged
//  - conv_s2 / denoise_conv1 / wb_reduce / wb_finalize / final_kernel =
//    round 13 verbatim (passed, 423us).
// d_out doubles as the I2 buffer.
// ---------------------------------------------------------------------------

#define BN_MUL 0.9999950000374997f   // 1/sqrt(1+1e-5)

static constexpr int BB   = 8;
static constexpr int HH   = 512;
static constexpr int WW   = 512;
static constexpr int HW   = HH * WW;
static constexpr int NTOK = 1024;    // (512/16)^2
static constexpr int DIMC = 64;
static constexpr int WBCH = 32;      // wb_reduce chunks per (b,c)

typedef _Float16 f16x8 __attribute__((ext_vector_type(8)));
typedef _Float16 f16x2 __attribute__((ext_vector_type(2)));
typedef float    f32x4 __attribute__((ext_vector_type(4)));

__device__ __forceinline__ float gelu_exact(float x) {
    return 0.5f * x * (1.0f + erff(x * 0.7071067811865476f));
}

// --- stride-2 3x3 conv + bias + BN (+ optional exact GELU), zero padding ---
// [round 6 verbatim] grid: (Hout*Wout/256, Cout/OCT, B).
template<int Cin, int Hin, int OCT, bool GELU>
__global__ __launch_bounds__(256) void conv_s2(const float* __restrict__ in,
                                               const float* __restrict__ wt,
                                               const float* __restrict__ bs,
                                               float* __restrict__ out)
{
    constexpr int Win  = Hin, Hout = Hin / 2, Wout = Hin / 2;
    constexpr int WSH  = (Wout == 256) ? 8 : (Wout == 128) ? 7 : (Wout == 64) ? 6 : 5;
    constexpr int PLANE = Hout * Wout;

    const int sp  = blockIdx.x * 256 + threadIdx.x;
    const int ow  = sp & (Wout - 1);
    const int oh  = sp >> WSH;
    const int oc0 = blockIdx.y * OCT;
    const int b   = blockIdx.z;
    const int Cout = (int)gridDim.y * OCT;

    float acc[OCT];
    #pragma unroll
    for (int o = 0; o < OCT; ++o) acc[o] = bs[oc0 + o];

    const int ih0 = oh * 2 - 1, iw0 = ow * 2 - 1;
    const float fh0 = (ih0 >= 0) ? 1.f : 0.f;
    const float fw0 = (iw0 >= 0) ? 1.f : 0.f;
    const int r0 = (ih0 >= 0) ? ih0 : 0;
    const int cc0 = (iw0 >= 0) ? iw0 : 0;

    const float* ip = in + (size_t)(b * Cin) * Hin * Win;
    #pragma unroll
    for (int ic = 0; ic < Cin; ++ic) {
        const float* pl = ip + ic * Hin * Win;
        const float* p0 = pl + r0 * Win;
        const float* p1 = pl + (ih0 + 1) * Win;
        const float* p2 = pl + (ih0 + 2) * Win;
        float  v00 = p0[cc0] * (fh0 * fw0);
        float2 va  = *(const float2*)(p0 + iw0 + 1);
        float  v01 = va.x * fh0, v02 = va.y * fh0;
        float  v10 = p1[cc0] * fw0;
        float2 vb  = *(const float2*)(p1 + iw0 + 1);
        float  v20 = p2[cc0] * fw0;
        float2 vc  = *(const float2*)(p2 + iw0 + 1);
        #pragma unroll
        for (int o = 0; o < OCT; ++o) {
            const float* wr = wt + ((oc0 + o) * Cin + ic) * 9;   // uniform -> s_load
            acc[o] += v00 * wr[0] + v01 * wr[1] + v02 * wr[2]
                    + v10 * wr[3] + vb.x * wr[4] + vb.y * wr[5]
                    + v20 * wr[6] + vc.x * wr[7] + vc.y * wr[8];
        }
    }
    #pragma unroll
    for (int o = 0; o < OCT; ++o) {
        float a = acc[o] * BN_MUL;
        if (GELU) a = gelu_exact(a);
        out[(size_t)(b * Cout + oc0 + o) * PLANE + sp] = a;
    }
}

// --- fused denoise + conv1_mp --- [round 6 verbatim]
__global__ __launch_bounds__(256) void denoise_conv1_kernel(
    const float* __restrict__ I1, const float* __restrict__ attno,
    const float* __restrict__ gain_base,
    const float* __restrict__ wt, const float* __restrict__ bs,
    float* __restrict__ I2, float* __restrict__ out)
{
    const int sp = blockIdx.x * 256 + threadIdx.x;
    const int ow = sp & 255;
    const int oh = sp >> 8;
    const int b  = blockIdx.z;

    const float o0 = attno[b * 4 + 0], o1 = attno[b * 4 + 1];
    const float o2 = attno[b * 4 + 2], o3 = attno[b * 4 + 3];
    const float r1 = 0.1f * o0 + 3.0f;
    const float r2 = 0.1f * o1 + 2.0f;
    const float g  = o2 + gain_base[0];
    const float sg = 1.0f / (1.0f + __expf(-o3));
    const float ex = __expf(-0.5f / (r1 * r1));
    const float nx = 1.0f / (2.0f * ex + 1.0f);
    const float ey = __expf(-0.5f / (r2 * r2));
    const float ny = 1.0f / (2.0f * ey + 1.0f);
    const float kx0 = ex * nx, kx1 = nx;
    const float ky0 = ey * ny, ky1 = ny;

    const int rbase = 2 * oh - 2, cbase = 2 * ow - 2;
    int ri[5], ci[5];
    #pragma unroll
    for (int i = 0; i < 5; ++i) {
        int r = rbase + i; ri[i] = r < 0 ? -r : (r > 511 ? 1022 - r : r);
        int c = cbase + i; ci[i] = c < 0 ? -c : (c > 511 ? 1022 - c : c);
    }
    const bool topE = (oh == 0), leftE = (ow == 0);

    float acc[8];
    #pragma unroll
    for (int o = 0; o < 8; ++o) acc[o] = bs[o];

    #pragma unroll
    for (int c = 0; c < 3; ++c) {
        const float* ip = I1 + ((size_t)b * 3 + c) * HW;
        float p[5][5];
        #pragma unroll
        for (int i = 0; i < 5; ++i) {
            const float* rp = ip + ri[i] * WW;
            #pragma unroll
            for (int j = 0; j < 5; ++j) p[i][j] = rp[ci[j]];
        }
        float hs[5][3];
        #pragma unroll
        for (int i = 0; i < 5; ++i)
            #pragma unroll
            for (int j = 0; j < 3; ++j)
                hs[i][j] = kx0 * (p[i][j] + p[i][j + 2]) + kx1 * p[i][j + 1];
        float w2[3][3];
        #pragma unroll
        for (int i = 0; i < 3; ++i)
            #pragma unroll
            for (int j = 0; j < 3; ++j) {
                float bl = g * (ky0 * (hs[i][j] + hs[i + 2][j]) + ky1 * hs[i + 1][j]);
                float val = bl + sg * (p[i + 1][j + 1] - bl);
                w2[i][j] = fminf(fmaxf(val, 1e-5f), 1.0f);
            }
        float* op = I2 + ((size_t)b * 3 + c) * HW + (2 * oh) * WW + 2 * ow;
        float2 w0v; w0v.x = w2[1][1]; w0v.y = w2[1][2];
        float2 w1v; w1v.x = w2[2][1]; w1v.y = w2[2][2];
        *(float2*)op        = w0v;
        *(float2*)(op + WW) = w1v;
        if (topE)  { w2[0][0] = 0.f; w2[0][1] = 0.f; w2[0][2] = 0.f; }
        if (leftE) { w2[0][0] = 0.f; w2[1][0] = 0.f; w2[2][0] = 0.f; }
        #pragma unroll
        for (int o = 0; o < 8; ++o) {
            const float* wr = wt + (o * 3 + c) * 9;          // uniform -> s_load
            acc[o] += w2[0][0] * wr[0] + w2[0][1] * wr[1] + w2[0][2] * wr[2]
                    + w2[1][0] * wr[3] + w2[1][1] * wr[4] + w2[1][2] * wr[5]
                    + w2[2][0] * wr[6] + w2[2][1] * wr[7] + w2[2][2] * wr[8];
        }
    }
    #pragma unroll
    for (int o = 0; o < 8; ++o)
        out[(b * 8 + o) * 65536 + sp] = gelu_exact(acc[o] * BN_MUL);
}

// --- fused attention (K,V folded), v2: coalesced PV + shuffle reductions ---
__global__ __launch_bounds__(1024) void attn_kernel(
    const float* __restrict__ dx, const float* __restrict__ q,
    const float* __restrict__ kw, const float* __restrict__ kb,
    const float* __restrict__ vw, const float* __restrict__ vb,
    const float* __restrict__ pw, const float* __restrict__ pb,
    const float* __restrict__ dw, const float* __restrict__ db,
    float* __restrict__ outv, int T)
{
    __shared__ float qk[DIMC];
    __shared__ float sc[NTOK];
    __shared__ float wredm[16];
    __shared__ float wreds[16];
    __shared__ float uN[DIMC];
    __shared__ float osh[DIMC];
    __shared__ float psh[DIMC];
    __shared__ float qkb_s;
    const int tid  = threadIdx.x;
    const int lane = tid & 63;
    const int wv   = tid >> 6;
    const int bt   = blockIdx.x;
    const int b = bt / T, t = bt - b * T;
    const float* qt = q + t * DIMC;

    if (tid < DIMC) {
        float s = 0.f;
        #pragma unroll
        for (int c = 0; c < DIMC; ++c) s += qt[c] * kw[c * DIMC + tid];
        qk[tid] = s;
    }
    if (tid == 1023) {
        float s = 0.f;
        #pragma unroll
        for (int c = 0; c < DIMC; ++c) s += qt[c] * kb[c];
        qkb_s = s;
    }
    __syncthreads();

    // scores: tid = token, coalesced along tokens
    const float* dp = dx + (size_t)(b * DIMC) * NTOK;
    float s = qkb_s;
    #pragma unroll
    for (int c = 0; c < DIMC; ++c) s += qk[c] * dp[c * NTOK + tid];
    s *= 0.125f;

    // block max: wave butterfly + 16-entry cross-wave
    float m = s;
    #pragma unroll
    for (int off = 32; off > 0; off >>= 1) m = fmaxf(m, __shfl_xor(m, off));
    if (lane == 0) wredm[wv] = m;
    __syncthreads();
    m = wredm[0];
    #pragma unroll
    for (int k = 1; k < 16; ++k) m = fmaxf(m, wredm[k]);

    // exp + block sum
    float e = __expf(s - m);
    sc[tid] = e;
    float ss = e;
    #pragma unroll
    for (int off = 32; off > 0; off >>= 1) ss += __shfl_xor(ss, off);
    if (lane == 0) wreds[wv] = ss;
    __syncthreads();                      // sc[] + wreds[] visible
    float Ssum = wreds[0];
    #pragma unroll
    for (int k = 1; k < 16; ++k) Ssum += wreds[k];

    // PV: wave wv owns channels 4*wv..4*wv+3; lanes iterate tokens (coalesced)
    #pragma unroll
    for (int cc = 0; cc < 4; ++cc) {
        const int c = wv * 4 + cc;
        const float* dr = dp + c * NTOK;
        float p = 0.f;
        #pragma unroll
        for (int k = 0; k < 16; ++k) p += sc[k * 64 + lane] * dr[k * 64 + lane];
        #pragma unroll
        for (int off = 32; off > 0; off >>= 1) p += __shfl_xor(p, off);
        if (lane == 0) uN[c] = p / Ssum;
    }
    __syncthreads();

    if (tid < DIMC) {
        float o = vb[tid];
        const float* vr = vw + tid * DIMC;
        #pragma unroll
        for (int cc = 0; cc < DIMC; ++cc) o += vr[cc] * uN[cc];
        osh[tid] = o;
    }
    __syncthreads();
    if (tid < DIMC) {
        float p = pb[tid];
        const float* pr = pw + tid * DIMC;
        #pragma unroll
        for (int cc = 0; cc < DIMC; ++cc) p += pr[cc] * osh[cc];
        psh[tid] = p;
    }
    __syncthreads();
    if (tid == 0) {
        float r = db[0];
        #pragma unroll
        for (int cc = 0; cc < DIMC; ++cc) r += psh[cc] * dw[cc];
        outv[bt] = r;
    }
}

// --- chunked sum of I2^dist per (b,c) --- [round 13 verbatim]
__global__ __launch_bounds__(256) void wb_reduce_kernel(const float* __restrict__ I2,
                                                        const float* __restrict__ attno,
                                                        float* __restrict__ part)
{
    __shared__ float red[256];
    const int bc = blockIdx.y;                 // b*3 + c
    const int b  = bc / 3;
    float d = attno[b * 10 + 9];
    d = fmaxf(d, 0.f) + 1.0f;
    constexpr int CHUNK = HW / WBCH;           // 8192 px
    const float4* base = (const float4*)(I2 + (size_t)bc * HW + blockIdx.x * CHUNK);
    float l = 0.f;
    #pragma unroll
    for (int i = threadIdx.x, it = 0; it < CHUNK / 4 / 256; ++it, i += 256) {
        float4 v = base[i];
        l += __expf(d * __logf(v.x)) + __expf(d * __logf(v.y))
           + __expf(d * __logf(v.z)) + __expf(d * __logf(v.w));
    }
    red[threadIdx.x] = l;
    __syncthreads();
    for (int off = 128; off > 0; off >>= 1) {
        if (threadIdx.x < off) red[threadIdx.x] += red[threadIdx.x + off];
        __syncthreads();
    }
    if (threadIdx.x == 0) part[bc * WBCH + blockIdx.x] = red[0];
}

// --- per-batch WB scale + NILUT w1..w3 f16 pre-conversion (256 thr) ---
__global__ void wb_finalize_kernel(const float* __restrict__ part,
                                   const float* __restrict__ attno,
                                   float* __restrict__ wbsc,
                                   const float* __restrict__ w1,
                                   const float* __restrict__ w2,
                                   const float* __restrict__ w3,
                                   _Float16* __restrict__ whf)
{
    const int t = threadIdx.x;
    // pre-convert the three 32x32 NILUT weight matrices to f16 (RTN, same
    // rounding as the previous per-pixel (_Float16) casts -> bit-identical)
    for (int i = t; i < 1024; i += 256) {
        whf[i]        = (_Float16)w1[i];
        whf[1024 + i] = (_Float16)w2[i];
        whf[2048 + i] = (_Float16)w3[i];
    }
    if (t < BB) {
        const int b = t;
        float d = attno[b * 10 + 9];
        d = fmaxf(d, 0.f) + 1.0f;
        float inv = 1.0f / d;
        float s[3];
        #pragma unroll
        for (int c = 0; c < 3; ++c) {
            float t0 = 0.f;
            const float* pp = part + (b * 3 + c) * WBCH;
            #pragma unroll
            for (int k = 0; k < WBCH; ++k) t0 += pp[k];
            s[c] = t0;
        }
        float avg = powf((s[0] + s[1] + s[2]) / (3.0f * (float)HW), inv);
        #pragma unroll
        for (int c = 0; c < 3; ++c)
            wbsc[b * 4 + c] = avg / powf(s[c] / (float)HW, inv);
    }
}

// --- fused WB + CCM + NILUT: layers 2-4 on MFMA f16, v4 --- [round 13 verbatim]
__global__ void __launch_bounds__(256) final_kernel(
    float* __restrict__ io,
    const float* __restrict__ wbsc, const float* __restrict__ attno,
    const _Float16* __restrict__ whf,
    const float* __restrict__ w0, const float* __restrict__ b0,
    const float* __restrict__ b1, const float* __restrict__ b2,
    const float* __restrict__ b3,
    const float* __restrict__ w4, const float* __restrict__ b4)
{
    constexpr int ROW = 40;                       // f16 per px row (80 B)
    __shared__ __align__(16) _Float16 LDS[4][64 * ROW];   // 20480 B
    const int tid  = threadIdx.x;
    const int wv   = tid >> 6;
    const int lane = tid & 63;
    const int nn   = lane & 15;
    const int quad = lane >> 4;
    _Float16* Wl = LDS[wv];

    const int b   = blockIdx.x >> 10;             // 1024 blocks per image
    const int pix = (blockIdx.x * 256 + tid) & (HW - 1);
    float* base = io + b * 3 * HW + pix;

    const float s0 = wbsc[b * 4 + 0], s1 = wbsc[b * 4 + 1], s2 = wbsc[b * 4 + 2];
    float v0 = base[0] * s0;
    float v1 = base[HW] * s1;
    float v2 = base[2 * HW] * s2;
    const float* o2p = attno + b * 10;            // block-uniform -> scalar
    float I4[3];
    #pragma unroll
    for (int d = 0; d < 3; ++d) {
        float m0 = 0.1f * o2p[d * 3]     + (d == 0 ? 1.f : 0.f);
        float m1 = 0.1f * o2p[d * 3 + 1] + (d == 1 ? 1.f : 0.f);
        float m2 = 0.1f * o2p[d * 3 + 2] + (d == 2 ? 1.f : 0.f);
        I4[d] = fminf(fmaxf(m0 * v0 + m1 * v1 + m2 * v2, 1e-5f), 1.0f);
    }

    #pragma unroll
    for (int j = 0; j < 32; j += 2) {
        float a0 = b0[j]   + w0[j*3]     * I4[0] + w0[j*3+1]     * I4[1] + w0[j*3+2]     * I4[2];
        float a1 = b0[j+1] + w0[(j+1)*3] * I4[0] + w0[(j+1)*3+1] * I4[1] + w0[(j+1)*3+2] * I4[2];
        f16x2 p;
        p[0] = (_Float16)fmaxf(a0, 0.f);
        p[1] = (_Float16)fmaxf(a1, 0.f);
        *(f16x2*)&Wl[lane * ROW + j] = p;
    }

    // weight fragments, pre-converted f16 (one 16B load each)
    f16x8 wf[3][2];
    float bv[3][2];
    const float* bls[3] = { b1, b2, b3 };
    #pragma unroll
    for (int L = 0; L < 3; ++L) {
        #pragma unroll
        for (int h = 0; h < 2; ++h) {
            wf[L][h] = *(const f16x8*)&whf[L * 1024 + (16 * h + nn) * 32 + quad * 8];
            bv[L][h] = bls[L][16 * h + nn];
        }
    }
    // layer-0 stores are wave-local: drain LDS queue instead of block barrier
    asm volatile("s_waitcnt lgkmcnt(0)" ::: "memory");
    __builtin_amdgcn_sched_barrier(0);

    #pragma unroll
    for (int L = 0; L < 3; ++L) {
        f16x8 af[4];
        #pragma unroll
        for (int t = 0; t < 4; ++t)
            af[t] = *(const f16x8*)&Wl[(16 * t + nn) * ROW + quad * 8];
        // af in regs before we overwrite the same region (wave-local WAR)
        asm volatile("s_waitcnt lgkmcnt(0)" ::: "memory");
        __builtin_amdgcn_sched_barrier(0);
        #pragma unroll
        for (int h = 0; h < 2; ++h) {
            f32x4 cb;
            cb[0] = cb[1] = cb[2] = cb[3] = bv[L][h];
            #pragma unroll
            for (int t = 0; t < 4; ++t) {
                f32x4 d = __builtin_amdgcn_mfma_f32_16x16x32_f16(af[t], wf[L][h], cb, 0, 0, 0);
                // tanh(x) = 1 - 2/(2^(x*2*log2e)+1); ONE v_rcp per quad.
                float a0 = __builtin_amdgcn_exp2f(d[0] * 2.8853900817779268f) + 1.0f;
                float a1 = __builtin_amdgcn_exp2f(d[1] * 2.8853900817779268f) + 1.0f;
                float a2 = __builtin_amdgcn_exp2f(d[2] * 2.8853900817779268f) + 1.0f;
                float a3 = __builtin_amdgcn_exp2f(d[3] * 2.8853900817779268f) + 1.0f;
                float p01 = a0 * a1, p23 = a2 * a3;
                float R   = __builtin_amdgcn_rcpf(p01 * p23);
                float r01 = R * p23, r23 = R * p01;   // 1/(a0a1), 1/(a2a3)
                Wl[(16 * t + quad * 4 + 0) * ROW + 16 * h + nn] = (_Float16)fmaf(-2.0f, r01 * a1, 1.0f);
                Wl[(16 * t + quad * 4 + 1) * ROW + 16 * h + nn] = (_Float16)fmaf(-2.0f, r01 * a0, 1.0f);
                Wl[(16 * t + quad * 4 + 2) * ROW + 16 * h + nn] = (_Float16)fmaf(-2.0f, r23 * a3, 1.0f);
                Wl[(16 * t + quad * 4 + 3) * ROW + 16 * h + nn] = (_Float16)fmaf(-2.0f, r23 * a2, 1.0f);
            }
        }
        // stores visible before next layer's reads (wave-local RAW)
        asm volatile("s_waitcnt lgkmcnt(0)" ::: "memory");
        __builtin_amdgcn_sched_barrier(0);
    }

    float h4[32];
    #pragma unroll
    for (int g = 0; g < 4; ++g) {
        f16x8 rv = *(const f16x8*)&Wl[lane * ROW + g * 8];
        #pragma unroll
        for (int i = 0; i < 8; ++i) h4[g * 8 + i] = (float)rv[i];
    }
    #pragma unroll
    for (int d = 0; d < 3; ++d) {
        float a = b4[d];
        const float* wr = w4 + d * 32;            // uniform -> s_load
        #pragma unroll
        for (int k = 0; k < 32; ++k) a += h4[k] * wr[k];
        a += I4[d];
        base[d * HW] = fminf(fmaxf(a, 0.f), 1.0f);
    }
}

extern "C" void kernel_launch(void* const* d_in, const int* in_sizes, int n_in,
                              void* d_out, int out_size, void* d_ws, size_t ws_size,
                              hipStream_t stream)
{
    const float* I1      = (const float*)d_in[0];
    const float* kp_q    = (const float*)d_in[1];
    const float* kp_c1w  = (const float*)d_in[2];  const float* kp_c1b = (const float*)d_in[3];
    const float* kp_c2w  = (const float*)d_in[4];  const float* kp_c2b = (const float*)d_in[5];
    const float* kp_c3w  = (const float*)d_in[6];  const float* kp_c3b = (const float*)d_in[7];
    const float* kp_c4w  = (const float*)d_in[8];  const float* kp_c4b = (const float*)d_in[9];
    const float* kp_kw   = (const float*)d_in[10]; const float* kp_vw  = (const float*)d_in[11];
    const float* kp_pw   = (const float*)d_in[12]; const float* kp_dw  = (const float*)d_in[13];
    const float* kp_kb   = (const float*)d_in[14]; const float* kp_vb  = (const float*)d_in[15];
    const float* kp_pb   = (const float*)d_in[16]; const float* kp_db  = (const float*)d_in[17];
    const float* mp_q    = (const float*)d_in[18];
    const float* mp_c1w  = (const float*)d_in[19]; const float* mp_c1b = (const float*)d_in[20];
    const float* mp_c2w  = (const float*)d_in[21]; const float* mp_c2b = (const float*)d_in[22];
    const float* mp_c3w  = (const float*)d_in[23]; const float* mp_c3b = (const float*)d_in[24];
    const float* mp_c4w  = (const float*)d_in[25]; const float* mp_c4b = (const float*)d_in[26];
    const float* mp_kw   = (const float*)d_in[27]; const float* mp_vw  = (const float*)d_in[28];
    const float* mp_pw   = (const float*)d_in[29]; const float* mp_dw  = (const float*)d_in[30];
    const float* mp_kb   = (const float*)d_in[31]; const float* mp_vb  = (const float*)d_in[32];
    const float* mp_pb   = (const float*)d_in[33]; const float* mp_db  = (const float*)d_in[34];
    const float* gainb   = (const float*)d_in[35];
    const float* lw0 = (const float*)d_in[36]; const float* lb0 = (const float*)d_in[37];
    const float* lw1 = (const float*)d_in[38]; const float* lb1 = (const float*)d_in[39];
    const float* lw2 = (const float*)d_in[40]; const float* lb2 = (const float*)d_in[41];
    const float* lw3 = (const float*)d_in[42]; const float* lb3 = (const float*)d_in[43];
    const float* lw4 = (const float*)d_in[44]; const float* lb4 = (const float*)d_in[45];

    float* ws    = (float*)d_ws;
    float* ds1   = ws;                          // 8*8*256*256   = 4194304
    float* ds2   = ds1 + 8 * 8 * 256 * 256;     // 8*16*128*128  = 2097152
    float* ds3   = ds2 + 8 * 16 * 128 * 128;    // 8*32*64*64    = 1048576
    float* ds4   = ds3 + 8 * 32 * 64 * 64;      // 8*64*32*32    = 524288
    float* attno = ds4 + 8 * 64 * 32 * 32;      // 128 (kp: b*4+t / mp: b*10+t)
    float* part  = attno + 128;                 // 24 * WBCH
    float* wbsc  = part + 24 * WBCH;            // 32
    float* I2    = (float*)d_out;               // I2 lives in d_out
    // f16 NILUT weights live in the (dead-by-then) ds1 region: 3072 f16
    _Float16* whf = (_Float16*)ds1;

    // --- Kernel_Predictor --- [round 6 configs]
    conv_s2<3, 512, 8, true ><<<dim3(256, 1, BB), 256, 0, stream>>>(I1,  kp_c1w, kp_c1b, ds1);
    conv_s2<8, 256, 8, true ><<<dim3(64,  2, BB), 256, 0, stream>>>(ds1, kp_c2w, kp_c2b, ds2);
    conv_s2<16, 128, 4, true><<<dim3(16,  8, BB), 256, 0, stream>>>(ds2, kp_c3w, kp_c3b, ds3);
    conv_s2<32, 64, 4, false><<<dim3(4,  16, BB), 256, 0, stream>>>(ds3, kp_c4w, kp_c4b, ds4);
    attn_kernel<<<BB * 4, 1024, 0, stream>>>(ds4, kp_q, kp_kw, kp_kb, kp_vw, kp_vb,
                                             kp_pw, kp_pb, kp_dw, kp_db, attno, 4);

    // --- denoise fused with conv1_mp: writes I2 (d_out) + ds1 ---
    denoise_conv1_kernel<<<dim3(256, 1, BB), 256, 0, stream>>>(I1, attno, gainb,
                                                               mp_c1w, mp_c1b, I2, ds1);

    // --- rest of Matrix_Predictor ---
    conv_s2<8, 256, 8, true ><<<dim3(64,  2, BB), 256, 0, stream>>>(ds1, mp_c2w, mp_c2b, ds2);
    conv_s2<16, 128, 4, true><<<dim3(16,  8, BB), 256, 0, stream>>>(ds2, mp_c3w, mp_c3b, ds3);
    conv_s2<32, 64, 4, false><<<dim3(4,  16, BB), 256, 0, stream>>>(ds3, mp_c4w, mp_c4b, ds4);
    attn_kernel<<<BB * 10, 1024, 0, stream>>>(ds4, mp_q, mp_kw, mp_kb, mp_vw, mp_vb,
                                              mp_pw, mp_pb, mp_dw, mp_db, attno, 10);

    // --- shades-of-gray reduction ---
    wb_reduce_kernel<<<dim3(WBCH, 24), 256, 0, stream>>>(I2, attno, part);
    wb_finalize_kernel<<<1, 256, 0, stream>>>(part, attno, wbsc, lw1, lw2, lw3, whf);

    // --- fused WB + CCM + NILUT (in-place on d_out) ---
    final_kernel<<<BB * HW / 256, 256, 0, stream>>>(I2, wbsc, attno, whf,
        lw0, lb0, lb1, lb2, lb3, lw4, lb4);
}